// Round 1
// baseline (740.143 us; speedup 1.0000x reference)
//
#include <hip/hip_runtime.h>
#include <cstddef>

#define HWN 65536              // 256*256
#define SCALE 0.35355339059327373f

typedef __bf16 bf16x8_t __attribute__((ext_vector_type(8)));
typedef float  f32x4_t  __attribute__((ext_vector_type(4)));

static __device__ __forceinline__ ushort f2bf(float f) {
    uint u = __float_as_uint(f);
    u = u + 0x7fffu + ((u >> 16) & 1u);   // RNE
    return (ushort)(u >> 16);
}
static __device__ __forceinline__ float bf2f(ushort b) {
    return __uint_as_float(((uint)b) << 16);
}

// ---------------------------------------------------------------------------
// Kernel 0: expand bias_table via rel_index into biasT[head][m][n] so the
// attention hot loop reads it with coalesced lane-contiguous loads.
// 8*64*64 floats = 128 KB; lives in the tail of d_out (dead until final GEMM).
// ---------------------------------------------------------------------------
__global__ __launch_bounds__(256) void bias_pre(
    const float* __restrict__ bt, const int* __restrict__ ri,
    float* __restrict__ biasT)
{
    int g = blockIdx.x * 256 + threadIdx.x;   // 0..32767
    int n = g & 63;
    int m = (g >> 6) & 63;
    int h = g >> 12;
    biasT[g] = bt[ri[n * 64 + m] * 8 + h];
}

// ---------------------------------------------------------------------------
// Kernel 1: 1x1 conv, 64 -> 64 channels (fp32, VALU).
// ---------------------------------------------------------------------------
__global__ __launch_bounds__(256) void conv1x1_64(
    const float* __restrict__ X, const float* __restrict__ W,
    float* __restrict__ Y)
{
    int gp = blockIdx.x * 256 + threadIdx.x;
    int b  = gp >> 16;
    int p  = gp & 65535;
    const float* Xb = X + (size_t)b * 64 * HWN + p;
    float* Yb       = Y + (size_t)b * 64 * HWN + p;

    float xr[64];
#pragma unroll
    for (int c = 0; c < 64; c++) xr[c] = Xb[(size_t)c * HWN];

#pragma unroll 4
    for (int o = 0; o < 64; o++) {
        const float* Wr = W + o * 64;
        float acc = 0.f;
#pragma unroll
        for (int c = 0; c < 64; c++) acc = fmaf(Wr[c], xr[c], acc);
        Yb[(size_t)o * HWN] = acc;
    }
}

// ---------------------------------------------------------------------------
// Kernel 2: 256->256 channel GEMM via bf16 MFMA (unchanged from R2).
// ---------------------------------------------------------------------------
template <typename XT, typename YT>
__global__ __launch_bounds__(256) void gemm256(
    const XT* __restrict__ X, const float* __restrict__ W, YT* __restrict__ Y)
{
    __shared__ ushort Al[128 * 72];   // [m][k], stride 72 bf16
    __shared__ ushort Bl[128 * 72];   // [n][k], swizzled 16B groups

    int b   = blockIdx.z;
    int oB  = blockIdx.y * 128;
    int pB  = blockIdx.x * 128;
    int tid = threadIdx.x;

    const XT* Xb = X + (size_t)b * 256 * HWN;
    YT*       Yb = Y + (size_t)b * 256 * HWN;

    int wv = tid >> 6, lane = tid & 63;
    int wm = (wv >> 1) * 64, wn = (wv & 1) * 64;
    int qd = lane >> 4, ln = lane & 15;

    int kgB = tid >> 4;
    int pgB = tid & 15;
    int p0  = pgB * 8;

    f32x4_t acc[4][4];
#pragma unroll
    for (int i = 0; i < 4; i++)
#pragma unroll
        for (int j = 0; j < 4; j++) acc[i][j] = {0.f, 0.f, 0.f, 0.f};

    for (int kc = 0; kc < 256; kc += 64) {
#pragma unroll
        for (int s = 0; s < 4; s++) {
            int u = tid + s * 256;
            int m = u >> 3, kg = u & 7;
            const float4* src = (const float4*)&W[(oB + m) * 256 + kc + kg * 8];
            float4 w0 = src[0], w1 = src[1];
            uint4 pk;
            pk.x = f2bf(w0.x) | ((uint)f2bf(w0.y) << 16);
            pk.y = f2bf(w0.z) | ((uint)f2bf(w0.w) << 16);
            pk.z = f2bf(w1.x) | ((uint)f2bf(w1.y) << 16);
            pk.w = f2bf(w1.z) | ((uint)f2bf(w1.w) << 16);
            *(uint4*)&Al[m * 72 + kg * 8] = pk;
        }
        ushort r[4][8];
#pragma unroll
        for (int i = 0; i < 4; i++) {
            int c = kc + kgB * 4 + i;
            if constexpr (sizeof(XT) == 4) {
                const float4* s = (const float4*)&Xb[(size_t)c * HWN + pB + p0];
                float4 x0 = s[0], x1 = s[1];
                r[i][0] = f2bf(x0.x); r[i][1] = f2bf(x0.y);
                r[i][2] = f2bf(x0.z); r[i][3] = f2bf(x0.w);
                r[i][4] = f2bf(x1.x); r[i][5] = f2bf(x1.y);
                r[i][6] = f2bf(x1.z); r[i][7] = f2bf(x1.w);
            } else {
                uint4 u = *(const uint4*)&Xb[(size_t)c * HWN + pB + p0];
                r[i][0] = u.x & 0xffff; r[i][1] = u.x >> 16;
                r[i][2] = u.y & 0xffff; r[i][3] = u.y >> 16;
                r[i][4] = u.z & 0xffff; r[i][5] = u.z >> 16;
                r[i][6] = u.w & 0xffff; r[i][7] = u.w >> 16;
            }
        }
        {
            int g   = kgB >> 1;
            int sub = (kgB & 1) * 4;
#pragma unroll
            for (int j = 0; j < 8; j++) {
                int n = p0 + j;
                ushort4 col = make_ushort4(r[0][j], r[1][j], r[2][j], r[3][j]);
                *(ushort4*)&Bl[n * 72 + ((g ^ (pgB & 7)) << 3) + sub] = col;
            }
        }
        __syncthreads();

#pragma unroll
        for (int ks = 0; ks < 2; ks++) {
            bf16x8_t af[4], bf[4];
#pragma unroll
            for (int i = 0; i < 4; i++)
                af[i] = *(const bf16x8_t*)&Al[(wm + i * 16 + ln) * 72 + ks * 32 + qd * 8];
#pragma unroll
            for (int j = 0; j < 4; j++) {
                int n = wn + j * 16 + ln;
                int g = ks * 4 + qd;
                bf[j] = *(const bf16x8_t*)&Bl[n * 72 + ((g ^ ((n >> 3) & 7)) << 3)];
            }
#pragma unroll
            for (int i = 0; i < 4; i++)
#pragma unroll
                for (int j = 0; j < 4; j++)
                    acc[i][j] = __builtin_amdgcn_mfma_f32_16x16x32_bf16(
                        af[i], bf[j], acc[i][j], 0, 0, 0);
        }
        __syncthreads();
    }

#pragma unroll
    for (int i = 0; i < 4; i++) {
#pragma unroll
        for (int j = 0; j < 4; j++) {
#pragma unroll
            for (int rr = 0; rr < 4; rr++) {
                int o = oB + wm + i * 16 + qd * 4 + rr;
                int p = pB + wn + j * 16 + ln;
                if constexpr (sizeof(YT) == 4)
                    Yb[(size_t)o * HWN + p] = acc[i][j][rr];
                else
                    Yb[(size_t)o * HWN + p] = f2bf(acc[i][j][rr]);
            }
        }
    }
}

// ---------------------------------------------------------------------------
// Kernel 3: windowed attention v2.  One wave per (window, head).
// QK + softmax in VALU (coalesced precomputed bias); PV via bf16 MFMA:
//   P (bf16) -> LDS rows -> A-frags; V B-frags loaded straight from global
//   (8 consecutive tokens = contiguous 16B per lane); C-layout -> LDS -> rows
//   so global stores stay coalesced.  OUT may alias VP (reads precede writes
//   within the block; blocks touch disjoint (window, head-channel) sets).
// ---------------------------------------------------------------------------
__global__ __launch_bounds__(64) void win_attn(
    const float* __restrict__ QP, const float* __restrict__ KP,
    const ushort* VP, ushort* OUT, const float* __restrict__ biasT)
{
    __shared__ float kl[64 * 8];
    __shared__ char  smem[64 * 72 * 2];        // pl (bf16) then reused as ol (f32)
    ushort* pl = (ushort*)smem;                // [n][m], stride 72
    float*  ol = (float*)smem;                 // [n][d], stride 36

    int bx   = blockIdx.x;
    int head = bx & 7;
    int win  = bx >> 3;
    int wc   = win & 31;
    int wr   = (win >> 5) & 31;
    int b    = win >> 10;

    int n   = threadIdx.x;
    int ws1 = n >> 3, ws2 = n & 7;
    int pos = (wr * 8 + ws1) * 256 + wc * 8 + ws2;

    const float*  qb = QP + ((size_t)(b * 64 + head * 8)) * HWN + pos;
    const float*  kb = KP + ((size_t)(b * 64 + head * 8)) * HWN + pos;
    const ushort* vbase = VP + ((size_t)(b * 256 + head * 32)) * HWN
                             + (size_t)(wr * 8) * 256 + wc * 8;
    ushort*       ob = OUT + ((size_t)(b * 256 + head * 32)) * HWN + pos;

    float qr[8];
#pragma unroll
    for (int d = 0; d < 8; d++) {
        qr[d] = qb[(size_t)d * HWN];
        kl[n * 8 + d] = kb[(size_t)d * HWN];
    }
    __syncthreads();

    // ---- QK^T + bias, softmax (lane n owns row n) ----
    const float* brow = biasT + head * 4096 + n;   // biasT[head][m][n]
    float attn[64];
    float mx = -1e30f;
#pragma unroll
    for (int m = 0; m < 64; m++) {
        float s = 0.f;
#pragma unroll
        for (int d = 0; d < 8; d++) s = fmaf(qr[d], kl[m * 8 + d], s);
        s = fmaf(s, SCALE, brow[m * 64]);
        attn[m] = s;
        mx = fmaxf(mx, s);
    }
    float sum = 0.f;
#pragma unroll
    for (int m = 0; m < 64; m++) {
        float e = __expf(attn[m] - mx);
        attn[m] = e;
        sum += e;
    }
    float rs = 1.f / sum;

    // ---- P -> LDS as bf16 rows ----
#pragma unroll
    for (int c = 0; c < 8; c++) {
        uint4 pk;
        pk.x = f2bf(attn[c*8+0] * rs) | ((uint)f2bf(attn[c*8+1] * rs) << 16);
        pk.y = f2bf(attn[c*8+2] * rs) | ((uint)f2bf(attn[c*8+3] * rs) << 16);
        pk.z = f2bf(attn[c*8+4] * rs) | ((uint)f2bf(attn[c*8+5] * rs) << 16);
        pk.w = f2bf(attn[c*8+6] * rs) | ((uint)f2bf(attn[c*8+7] * rs) << 16);
        *(uint4*)&pl[n * 72 + c * 8] = pk;
    }
    __syncthreads();

    // ---- PV via MFMA: O[n][d] = sum_m P[n][m] V[m][d] ----
    int ln = n & 15, qd = n >> 4;
    f32x4_t acc[4][2];
#pragma unroll
    for (int i = 0; i < 4; i++)
#pragma unroll
        for (int j = 0; j < 2; j++) acc[i][j] = {0.f, 0.f, 0.f, 0.f};

#pragma unroll
    for (int kc = 0; kc < 2; kc++) {
        bf16x8_t af[4], bf[2];
#pragma unroll
        for (int i = 0; i < 4; i++)
            af[i] = *(const bf16x8_t*)&pl[(16 * i + ln) * 72 + kc * 32 + qd * 8];
#pragma unroll
        for (int j = 0; j < 2; j++) {
            // B[d=16j+ln][k=m]: 8 consecutive tokens, contiguous 16B in global
            const ushort* vp8 = vbase + (size_t)(16 * j + ln) * HWN
                                      + (kc * 4 + qd) * 256;
            uint4 u = *(const uint4*)vp8;
            bf[j] = *(const bf16x8_t*)&u;
        }
#pragma unroll
        for (int i = 0; i < 4; i++)
#pragma unroll
            for (int j = 0; j < 2; j++)
                acc[i][j] = __builtin_amdgcn_mfma_f32_16x16x32_bf16(
                    af[i], bf[j], acc[i][j], 0, 0, 0);
    }
    __syncthreads();   // pl fully consumed; reuse smem as ol

    // ---- C-layout -> LDS -> per-lane rows, coalesced stores ----
#pragma unroll
    for (int i = 0; i < 4; i++)
#pragma unroll
        for (int j = 0; j < 2; j++)
#pragma unroll
            for (int r = 0; r < 4; r++)
                ol[(16 * i + qd * 4 + r) * 36 + j * 16 + ln] = acc[i][j][r];
    __syncthreads();

#pragma unroll
    for (int c = 0; c < 8; c++) {
        float4 o4 = *(const float4*)&ol[n * 36 + c * 4];
        ob[(size_t)(c * 4 + 0) * HWN] = f2bf(o4.x);
        ob[(size_t)(c * 4 + 1) * HWN] = f2bf(o4.y);
        ob[(size_t)(c * 4 + 2) * HWN] = f2bf(o4.z);
        ob[(size_t)(c * 4 + 3) * HWN] = f2bf(o4.w);
    }
}

// ---------------------------------------------------------------------------
// Kernel 4: reflect-pad + 8x8 depthwise conv + BN.  bf16 in/out, fp32 math.
// R3: row loads are 3x ds_read_b128 (float4) instead of 11x ds_read_b32.
//   Old scalar pattern: bank = (8*sy+4*sxg)%32 -> only 8 banks hit -> 8-way
//   conflict on every one of 88 scalar reads (4.7e7 conflict cycles).
//   b128 pattern: 64 lanes x 4 banks = uniform 8 accesses on each of the 32
//   banks = distribution optimum; 24 LDS instrs/thread instead of 88.
//   Stride stays 40 floats (160 B) so every float4 is 16 B aligned (sx%4==0).
// ---------------------------------------------------------------------------
__global__ __launch_bounds__(256) void dwconv_bn(
    const ushort* __restrict__ A, const float* __restrict__ DW,
    const float* __restrict__ gamma, const float* __restrict__ beta,
    const float* __restrict__ mean, const float* __restrict__ var,
    ushort* __restrict__ O)
{
    __shared__ float til[39 * 40];

    int c  = blockIdx.y;
    int b  = blockIdx.z;
    int tY = (blockIdx.x >> 3) * 32;
    int tX = (blockIdx.x & 7) * 32;
    int tid = threadIdx.x;

    const ushort* Ab = A + ((size_t)(b * 256 + c)) * HWN;

    for (int li = tid; li < 39 * 39; li += 256) {
        int r  = li / 39, cc = li - r * 39;
        int iy = tY - 3 + r;
        int ix = tX - 3 + cc;
        float v = 0.f;
        if (iy >= 0 && iy <= 256 && ix >= 0 && ix <= 256) {
            int sy = (iy == 256) ? 254 : iy;
            int sx = (ix == 256) ? 254 : ix;
            v = bf2f(Ab[sy * 256 + sx]);
        }
        til[r * 40 + cc] = v;
    }
    __syncthreads();

    float inv = gamma[c] * rsqrtf(var[c] + 1e-5f);
    float add = fmaf(-mean[c], inv, beta[c]);

    int sx = (tid & 7) * 4;
    int sy = tid >> 3;
    const float* dwc = DW + c * 64;

    float a0 = 0.f, a1 = 0.f, a2 = 0.f, a3 = 0.f;
#pragma unroll
    for (int ky = 0; ky < 8; ky++) {
        // 16B-aligned vector reads: (sy+ky)*40 + sx is a multiple of 4 floats.
        const float4* rp = (const float4*)&til[(sy + ky) * 40 + sx];
        float4 q0 = rp[0], q1 = rp[1], q2 = rp[2];
        float r[12] = {q0.x, q0.y, q0.z, q0.w,
                       q1.x, q1.y, q1.z, q1.w,
                       q2.x, q2.y, q2.z, q2.w};   // r[11] pad, never used in FMA
#pragma unroll
        for (int kx = 0; kx < 8; kx++) {
            float w = dwc[ky * 8 + kx];
            a0 = fmaf(r[kx + 0], w, a0);
            a1 = fmaf(r[kx + 1], w, a1);
            a2 = fmaf(r[kx + 2], w, a2);
            a3 = fmaf(r[kx + 3], w, a3);
        }
    }

    ushort4 r4 = make_ushort4(f2bf(fmaf(a0, inv, add)), f2bf(fmaf(a1, inv, add)),
                              f2bf(fmaf(a2, inv, add)), f2bf(fmaf(a3, inv, add)));
    *(ushort4*)&O[((size_t)(b * 256 + c)) * HWN + (tY + sy) * 256 + tX + sx] = r4;
}

// ---------------------------------------------------------------------------
// Workspace (192 MiB): qp f32 | kp f32 | vp bf16 (aliased by attn out) | dwo.
// biasT (128 KB) lives in the tail of d_out — dead until the final GEMM,
// which overwrites it after win_attn has consumed it.
// ---------------------------------------------------------------------------
extern "C" void kernel_launch(void* const* d_in, const int* in_sizes, int n_in,
                              void* d_out, int out_size, void* d_ws, size_t ws_size,
                              hipStream_t stream)
{
    (void)in_sizes; (void)n_in; (void)ws_size;

    const float* q    = (const float*)d_in[0];
    const float* v    = (const float*)d_in[1];
    const float* Wq   = (const float*)d_in[2];
    const float* Wk   = (const float*)d_in[3];
    const float* Wv   = (const float*)d_in[4];
    const float* bt   = (const float*)d_in[5];
    const float* dw   = (const float*)d_in[6];
    const float* gam  = (const float*)d_in[7];
    const float* bet  = (const float*)d_in[8];
    const float* mean = (const float*)d_in[9];
    const float* var  = (const float*)d_in[10];
    const float* pw   = (const float*)d_in[11];
    const int*   ri   = (const int*)d_in[12];
    float* out = (float*)d_out;

    float*  qp  = (float*)d_ws;
    float*  kp  = qp + (size_t)2 * 64 * HWN;
    ushort* vp  = (ushort*)(kp + (size_t)2 * 64 * HWN);
    ushort* ao  = vp;                          // alias, see win_attn comment
    ushort* dwo = vp + (size_t)2 * 256 * HWN;
    float*  biasT = out + (size_t)out_size - 32768;

    bias_pre<<<128, 256, 0, stream>>>(bt, ri, biasT);
    conv1x1_64<<<512, 256, 0, stream>>>(q, Wq, qp);
    conv1x1_64<<<512, 256, 0, stream>>>(qp, Wk, kp);
    gemm256<float, ushort><<<dim3(512, 2, 2), 256, 0, stream>>>(v, Wv, vp);
    win_attn<<<16384, 64, 0, stream>>>(qp, kp, vp, ao, biasT);
    dwconv_bn<<<dim3(64, 256, 2), 256, 0, stream>>>(ao, dw, gam, bet, mean, var, dwo);
    gemm256<ushort, float><<<dim3(512, 2, 2), 256, 0, stream>>>(dwo, pw, out);
}

// Round 2
// 693.242 us; speedup vs baseline: 1.0677x; 1.0677x over previous
//
#include <hip/hip_runtime.h>
#include <cstddef>

#define HWN 65536              // 256*256
#define SCALE 0.35355339059327373f

typedef __bf16 bf16x8_t __attribute__((ext_vector_type(8)));
typedef float  f32x4_t  __attribute__((ext_vector_type(4)));

static __device__ __forceinline__ ushort f2bf(float f) {
    uint u = __float_as_uint(f);
    u = u + 0x7fffu + ((u >> 16) & 1u);   // RNE
    return (ushort)(u >> 16);
}
static __device__ __forceinline__ float bf2f(ushort b) {
    return __uint_as_float(((uint)b) << 16);
}

// ---------------------------------------------------------------------------
// Kernel 0: expand bias_table via rel_index into biasT[head][m][n] so the
// attention hot loop reads it with coalesced lane-contiguous loads.
// 8*64*64 floats = 128 KB; lives in the tail of d_out (dead until final GEMM).
// ---------------------------------------------------------------------------
__global__ __launch_bounds__(256) void bias_pre(
    const float* __restrict__ bt, const int* __restrict__ ri,
    float* __restrict__ biasT)
{
    int g = blockIdx.x * 256 + threadIdx.x;   // 0..32767
    int n = g & 63;
    int m = (g >> 6) & 63;
    int h = g >> 12;
    biasT[g] = bt[ri[n * 64 + m] * 8 + h];
}

// ---------------------------------------------------------------------------
// Kernel 1: 1x1 conv, 64 -> 64 channels (fp32, VALU).
// ---------------------------------------------------------------------------
__global__ __launch_bounds__(256) void conv1x1_64(
    const float* __restrict__ X, const float* __restrict__ W,
    float* __restrict__ Y)
{
    int gp = blockIdx.x * 256 + threadIdx.x;
    int b  = gp >> 16;
    int p  = gp & 65535;
    const float* Xb = X + (size_t)b * 64 * HWN + p;
    float* Yb       = Y + (size_t)b * 64 * HWN + p;

    float xr[64];
#pragma unroll
    for (int c = 0; c < 64; c++) xr[c] = Xb[(size_t)c * HWN];

#pragma unroll 4
    for (int o = 0; o < 64; o++) {
        const float* Wr = W + o * 64;
        float acc = 0.f;
#pragma unroll
        for (int c = 0; c < 64; c++) acc = fmaf(Wr[c], xr[c], acc);
        Yb[(size_t)o * HWN] = acc;
    }
}

// ---------------------------------------------------------------------------
// Kernel 2: 256->256 channel GEMM via bf16 MFMA (unchanged from R2).
// ---------------------------------------------------------------------------
template <typename XT, typename YT>
__global__ __launch_bounds__(256) void gemm256(
    const XT* __restrict__ X, const float* __restrict__ W, YT* __restrict__ Y)
{
    __shared__ ushort Al[128 * 72];   // [m][k], stride 72 bf16
    __shared__ ushort Bl[128 * 72];   // [n][k], swizzled 16B groups

    int b   = blockIdx.z;
    int oB  = blockIdx.y * 128;
    int pB  = blockIdx.x * 128;
    int tid = threadIdx.x;

    const XT* Xb = X + (size_t)b * 256 * HWN;
    YT*       Yb = Y + (size_t)b * 256 * HWN;

    int wv = tid >> 6, lane = tid & 63;
    int wm = (wv >> 1) * 64, wn = (wv & 1) * 64;
    int qd = lane >> 4, ln = lane & 15;

    int kgB = tid >> 4;
    int pgB = tid & 15;
    int p0  = pgB * 8;

    f32x4_t acc[4][4];
#pragma unroll
    for (int i = 0; i < 4; i++)
#pragma unroll
        for (int j = 0; j < 4; j++) acc[i][j] = {0.f, 0.f, 0.f, 0.f};

    for (int kc = 0; kc < 256; kc += 64) {
#pragma unroll
        for (int s = 0; s < 4; s++) {
            int u = tid + s * 256;
            int m = u >> 3, kg = u & 7;
            const float4* src = (const float4*)&W[(oB + m) * 256 + kc + kg * 8];
            float4 w0 = src[0], w1 = src[1];
            uint4 pk;
            pk.x = f2bf(w0.x) | ((uint)f2bf(w0.y) << 16);
            pk.y = f2bf(w0.z) | ((uint)f2bf(w0.w) << 16);
            pk.z = f2bf(w1.x) | ((uint)f2bf(w1.y) << 16);
            pk.w = f2bf(w1.z) | ((uint)f2bf(w1.w) << 16);
            *(uint4*)&Al[m * 72 + kg * 8] = pk;
        }
        ushort r[4][8];
#pragma unroll
        for (int i = 0; i < 4; i++) {
            int c = kc + kgB * 4 + i;
            if constexpr (sizeof(XT) == 4) {
                const float4* s = (const float4*)&Xb[(size_t)c * HWN + pB + p0];
                float4 x0 = s[0], x1 = s[1];
                r[i][0] = f2bf(x0.x); r[i][1] = f2bf(x0.y);
                r[i][2] = f2bf(x0.z); r[i][3] = f2bf(x0.w);
                r[i][4] = f2bf(x1.x); r[i][5] = f2bf(x1.y);
                r[i][6] = f2bf(x1.z); r[i][7] = f2bf(x1.w);
            } else {
                uint4 u = *(const uint4*)&Xb[(size_t)c * HWN + pB + p0];
                r[i][0] = u.x & 0xffff; r[i][1] = u.x >> 16;
                r[i][2] = u.y & 0xffff; r[i][3] = u.y >> 16;
                r[i][4] = u.z & 0xffff; r[i][5] = u.z >> 16;
                r[i][6] = u.w & 0xffff; r[i][7] = u.w >> 16;
            }
        }
        {
            int g   = kgB >> 1;
            int sub = (kgB & 1) * 4;
#pragma unroll
            for (int j = 0; j < 8; j++) {
                int n = p0 + j;
                ushort4 col = make_ushort4(r[0][j], r[1][j], r[2][j], r[3][j]);
                *(ushort4*)&Bl[n * 72 + ((g ^ (pgB & 7)) << 3) + sub] = col;
            }
        }
        __syncthreads();

#pragma unroll
        for (int ks = 0; ks < 2; ks++) {
            bf16x8_t af[4], bf[4];
#pragma unroll
            for (int i = 0; i < 4; i++)
                af[i] = *(const bf16x8_t*)&Al[(wm + i * 16 + ln) * 72 + ks * 32 + qd * 8];
#pragma unroll
            for (int j = 0; j < 4; j++) {
                int n = wn + j * 16 + ln;
                int g = ks * 4 + qd;
                bf[j] = *(const bf16x8_t*)&Bl[n * 72 + ((g ^ ((n >> 3) & 7)) << 3)];
            }
#pragma unroll
            for (int i = 0; i < 4; i++)
#pragma unroll
                for (int j = 0; j < 4; j++)
                    acc[i][j] = __builtin_amdgcn_mfma_f32_16x16x32_bf16(
                        af[i], bf[j], acc[i][j], 0, 0, 0);
        }
        __syncthreads();
    }

#pragma unroll
    for (int i = 0; i < 4; i++) {
#pragma unroll
        for (int j = 0; j < 4; j++) {
#pragma unroll
            for (int rr = 0; rr < 4; rr++) {
                int o = oB + wm + i * 16 + qd * 4 + rr;
                int p = pB + wn + j * 16 + ln;
                if constexpr (sizeof(YT) == 4)
                    Yb[(size_t)o * HWN + p] = acc[i][j][rr];
                else
                    Yb[(size_t)o * HWN + p] = f2bf(acc[i][j][rr]);
            }
        }
    }
}

// ---------------------------------------------------------------------------
// Kernel 3: windowed attention v2.  One wave per (window, head).
// QK + softmax in VALU (coalesced precomputed bias); PV via bf16 MFMA:
//   P (bf16) -> LDS rows -> A-frags; V B-frags loaded straight from global
//   (8 consecutive tokens = contiguous 16B per lane); C-layout -> LDS -> rows
//   so global stores stay coalesced.  OUT may alias VP (reads precede writes
//   within the block; blocks touch disjoint (window, head-channel) sets).
// ---------------------------------------------------------------------------
__global__ __launch_bounds__(64) void win_attn(
    const float* __restrict__ QP, const float* __restrict__ KP,
    const ushort* VP, ushort* OUT, const float* __restrict__ biasT)
{
    __shared__ float kl[64 * 8];
    __shared__ char  smem[64 * 72 * 2];        // pl (bf16) then reused as ol (f32)
    ushort* pl = (ushort*)smem;                // [n][m], stride 72
    float*  ol = (float*)smem;                 // [n][d], stride 36

    int bx   = blockIdx.x;
    int head = bx & 7;
    int win  = bx >> 3;
    int wc   = win & 31;
    int wr   = (win >> 5) & 31;
    int b    = win >> 10;

    int n   = threadIdx.x;
    int ws1 = n >> 3, ws2 = n & 7;
    int pos = (wr * 8 + ws1) * 256 + wc * 8 + ws2;

    const float*  qb = QP + ((size_t)(b * 64 + head * 8)) * HWN + pos;
    const float*  kb = KP + ((size_t)(b * 64 + head * 8)) * HWN + pos;
    const ushort* vbase = VP + ((size_t)(b * 256 + head * 32)) * HWN
                             + (size_t)(wr * 8) * 256 + wc * 8;
    ushort*       ob = OUT + ((size_t)(b * 256 + head * 32)) * HWN + pos;

    float qr[8];
#pragma unroll
    for (int d = 0; d < 8; d++) {
        qr[d] = qb[(size_t)d * HWN];
        kl[n * 8 + d] = kb[(size_t)d * HWN];
    }
    __syncthreads();

    // ---- QK^T + bias, softmax (lane n owns row n) ----
    const float* brow = biasT + head * 4096 + n;   // biasT[head][m][n]
    float attn[64];
    float mx = -1e30f;
#pragma unroll
    for (int m = 0; m < 64; m++) {
        float s = 0.f;
#pragma unroll
        for (int d = 0; d < 8; d++) s = fmaf(qr[d], kl[m * 8 + d], s);
        s = fmaf(s, SCALE, brow[m * 64]);
        attn[m] = s;
        mx = fmaxf(mx, s);
    }
    float sum = 0.f;
#pragma unroll
    for (int m = 0; m < 64; m++) {
        float e = __expf(attn[m] - mx);
        attn[m] = e;
        sum += e;
    }
    float rs = 1.f / sum;

    // ---- P -> LDS as bf16 rows ----
#pragma unroll
    for (int c = 0; c < 8; c++) {
        uint4 pk;
        pk.x = f2bf(attn[c*8+0] * rs) | ((uint)f2bf(attn[c*8+1] * rs) << 16);
        pk.y = f2bf(attn[c*8+2] * rs) | ((uint)f2bf(attn[c*8+3] * rs) << 16);
        pk.z = f2bf(attn[c*8+4] * rs) | ((uint)f2bf(attn[c*8+5] * rs) << 16);
        pk.w = f2bf(attn[c*8+6] * rs) | ((uint)f2bf(attn[c*8+7] * rs) << 16);
        *(uint4*)&pl[n * 72 + c * 8] = pk;
    }
    __syncthreads();

    // ---- PV via MFMA: O[n][d] = sum_m P[n][m] V[m][d] ----
    int ln = n & 15, qd = n >> 4;
    f32x4_t acc[4][2];
#pragma unroll
    for (int i = 0; i < 4; i++)
#pragma unroll
        for (int j = 0; j < 2; j++) acc[i][j] = {0.f, 0.f, 0.f, 0.f};

#pragma unroll
    for (int kc = 0; kc < 2; kc++) {
        bf16x8_t af[4], bf[2];
#pragma unroll
        for (int i = 0; i < 4; i++)
            af[i] = *(const bf16x8_t*)&pl[(16 * i + ln) * 72 + kc * 32 + qd * 8];
#pragma unroll
        for (int j = 0; j < 2; j++) {
            // B[d=16j+ln][k=m]: 8 consecutive tokens, contiguous 16B in global
            const ushort* vp8 = vbase + (size_t)(16 * j + ln) * HWN
                                      + (kc * 4 + qd) * 256;
            uint4 u = *(const uint4*)vp8;
            bf[j] = *(const bf16x8_t*)&u;
        }
#pragma unroll
        for (int i = 0; i < 4; i++)
#pragma unroll
            for (int j = 0; j < 2; j++)
                acc[i][j] = __builtin_amdgcn_mfma_f32_16x16x32_bf16(
                    af[i], bf[j], acc[i][j], 0, 0, 0);
    }
    __syncthreads();   // pl fully consumed; reuse smem as ol

    // ---- C-layout -> LDS -> per-lane rows, coalesced stores ----
#pragma unroll
    for (int i = 0; i < 4; i++)
#pragma unroll
        for (int j = 0; j < 2; j++)
#pragma unroll
            for (int r = 0; r < 4; r++)
                ol[(16 * i + qd * 4 + r) * 36 + j * 16 + ln] = acc[i][j][r];
    __syncthreads();

#pragma unroll
    for (int c = 0; c < 8; c++) {
        float4 o4 = *(const float4*)&ol[n * 36 + c * 4];
        ob[(size_t)(c * 4 + 0) * HWN] = f2bf(o4.x);
        ob[(size_t)(c * 4 + 1) * HWN] = f2bf(o4.y);
        ob[(size_t)(c * 4 + 2) * HWN] = f2bf(o4.z);
        ob[(size_t)(c * 4 + 3) * HWN] = f2bf(o4.w);
    }
}

// ---------------------------------------------------------------------------
// Kernel 4: reflect-pad + 8x8 depthwise conv + BN.  bf16 in/out, fp32 math.
// R4: register blocking.  R1/R3 post-mortem showed the kernel is VALU-bound
// on per-output overhead (~960 VALU instr per 4 outputs; FMA floor is 27 us
// but we ran at 153 us).  Now each thread computes a 4-wide x 8-tall strip
// (32 outputs): 2048 FMA vs ~45 ds_read_b128 + ~40 loader instrs, so the
// FMA payload dominates the instruction stream.
//   block tile: 128 wide x 64 tall (8192 outputs, 256 threads)
//   LDS: 71 x 136 f32 = 38.6 KB (4 blocks/CU)
//   weights: uniform per block -> s_loads, hoisted out of the loop
// ---------------------------------------------------------------------------
__global__ __launch_bounds__(256) void dwconv_bn(
    const ushort* __restrict__ A, const float* __restrict__ DW,
    const float* __restrict__ gamma, const float* __restrict__ beta,
    const float* __restrict__ mean, const float* __restrict__ var,
    ushort* __restrict__ O)
{
    __shared__ float til[71 * 136];

    int c  = blockIdx.y;
    int b  = blockIdx.z;
    int tX = (blockIdx.x & 1) * 128;
    int tY = (blockIdx.x >> 1) * 64;
    int tid = threadIdx.x;

    const ushort* Ab = A + ((size_t)(b * 256 + c)) * HWN;

    // ---- tile load: 71 rows x 17 ushort8-chunks (136 cols incl. slack) ----
    for (int li = tid; li < 71 * 17; li += 256) {
        int yr = li / 17;
        int ck = li - yr * 17;
        int iy = tY - 3 + yr;
        int xb = tX - 3 + ck * 8;
        float vals[8];
        if (iy < 0 || iy > 256) {
#pragma unroll
            for (int e = 0; e < 8; e++) vals[e] = 0.f;
        } else {
            int sy = (iy == 256) ? 254 : iy;
            const ushort* row = Ab + sy * 256;
            if (xb >= 0 && xb + 7 <= 255) {
                uint4 u = *(const uint4*)&row[xb];
                vals[0] = bf2f(u.x & 0xffff); vals[1] = bf2f(u.x >> 16);
                vals[2] = bf2f(u.y & 0xffff); vals[3] = bf2f(u.y >> 16);
                vals[4] = bf2f(u.z & 0xffff); vals[5] = bf2f(u.z >> 16);
                vals[6] = bf2f(u.w & 0xffff); vals[7] = bf2f(u.w >> 16);
            } else {
#pragma unroll
                for (int e = 0; e < 8; e++) {
                    int ix = xb + e;
                    if (ix < 0 || ix > 256) vals[e] = 0.f;
                    else vals[e] = bf2f(row[(ix == 256) ? 254 : ix]);
                }
            }
        }
        float4 lo = {vals[0], vals[1], vals[2], vals[3]};
        float4 hi = {vals[4], vals[5], vals[6], vals[7]};
        *(float4*)&til[yr * 136 + ck * 8]     = lo;
        *(float4*)&til[yr * 136 + ck * 8 + 4] = hi;
    }

    // ---- weights: uniform address -> scalar loads ----
    float w[64];
#pragma unroll
    for (int i = 0; i < 16; i++)
        *(float4*)&w[i * 4] = *(const float4*)&DW[c * 64 + i * 4];

    __syncthreads();

    float inv = gamma[c] * rsqrtf(var[c] + 1e-5f);
    float add = fmaf(-mean[c], inv, beta[c]);

    int xg = tid & 31;       // 32 x-groups * 4 wide = 128
    int yg = tid >> 5;       // 8  y-groups * 8 tall = 64
    int xo = xg * 4;         // tile col of output 0 (also til col offset)
    int yb = yg * 8;         // tile row of output 0

    float acc[8][4];
#pragma unroll
    for (int j = 0; j < 8; j++)
#pragma unroll
        for (int p = 0; p < 4; p++) acc[j][p] = 0.f;

#pragma unroll
    for (int r = 0; r < 15; r++) {
        const float4* rp = (const float4*)&til[(yb + r) * 136 + xo];
        float4 q0 = rp[0], q1 = rp[1], q2 = rp[2];
        float row[12] = {q0.x, q0.y, q0.z, q0.w,
                         q1.x, q1.y, q1.z, q1.w,
                         q2.x, q2.y, q2.z, q2.w};   // row[11] slack, unused
        int jlo = (r - 7 < 0) ? 0 : r - 7;
        int jhi = (r < 7) ? r : 7;
#pragma unroll
        for (int j = jlo; j <= jhi; j++) {
            const float* wr = &w[(r - j) * 8];
#pragma unroll
            for (int kx = 0; kx < 8; kx++) {
                float wt = wr[kx];
                acc[j][0] = fmaf(row[kx + 0], wt, acc[j][0]);
                acc[j][1] = fmaf(row[kx + 1], wt, acc[j][1]);
                acc[j][2] = fmaf(row[kx + 2], wt, acc[j][2]);
                acc[j][3] = fmaf(row[kx + 3], wt, acc[j][3]);
            }
        }
    }

    ushort* Ob = O + ((size_t)(b * 256 + c)) * HWN;
#pragma unroll
    for (int j = 0; j < 8; j++) {
        ushort4 r4 = make_ushort4(
            f2bf(fmaf(acc[j][0], inv, add)), f2bf(fmaf(acc[j][1], inv, add)),
            f2bf(fmaf(acc[j][2], inv, add)), f2bf(fmaf(acc[j][3], inv, add)));
        *(ushort4*)&Ob[(tY + yb + j) * 256 + tX + xo] = r4;
    }
}

// ---------------------------------------------------------------------------
// Workspace (192 MiB): qp f32 | kp f32 | vp bf16 (aliased by attn out) | dwo.
// biasT (128 KB) lives in the tail of d_out — dead until the final GEMM,
// which overwrites it after win_attn has consumed it.
// ---------------------------------------------------------------------------
extern "C" void kernel_launch(void* const* d_in, const int* in_sizes, int n_in,
                              void* d_out, int out_size, void* d_ws, size_t ws_size,
                              hipStream_t stream)
{
    (void)in_sizes; (void)n_in; (void)ws_size;

    const float* q    = (const float*)d_in[0];
    const float* v    = (const float*)d_in[1];
    const float* Wq   = (const float*)d_in[2];
    const float* Wk   = (const float*)d_in[3];
    const float* Wv   = (const float*)d_in[4];
    const float* bt   = (const float*)d_in[5];
    const float* dw   = (const float*)d_in[6];
    const float* gam  = (const float*)d_in[7];
    const float* bet  = (const float*)d_in[8];
    const float* mean = (const float*)d_in[9];
    const float* var  = (const float*)d_in[10];
    const float* pw   = (const float*)d_in[11];
    const int*   ri   = (const int*)d_in[12];
    float* out = (float*)d_out;

    float*  qp  = (float*)d_ws;
    float*  kp  = qp + (size_t)2 * 64 * HWN;
    ushort* vp  = (ushort*)(kp + (size_t)2 * 64 * HWN);
    ushort* ao  = vp;                          // alias, see win_attn comment
    ushort* dwo = vp + (size_t)2 * 256 * HWN;
    float*  biasT = out + (size_t)out_size - 32768;

    bias_pre<<<128, 256, 0, stream>>>(bt, ri, biasT);
    conv1x1_64<<<512, 256, 0, stream>>>(q, Wq, qp);
    conv1x1_64<<<512, 256, 0, stream>>>(qp, Wk, kp);
    gemm256<float, ushort><<<dim3(512, 2, 2), 256, 0, stream>>>(v, Wv, vp);
    win_attn<<<16384, 64, 0, stream>>>(qp, kp, vp, ao, biasT);
    dwconv_bn<<<dim3(8, 256, 2), 256, 0, stream>>>(ao, dw, gam, bet, mean, var, dwo);
    gemm256<ushort, float><<<dim3(512, 2, 2), 256, 0, stream>>>(dwo, pw, out);
}

// Round 3
// 648.200 us; speedup vs baseline: 1.1418x; 1.0695x over previous
//
#include <hip/hip_runtime.h>
#include <cstddef>

#define HWN 65536              // 256*256
#define SCALE 0.35355339059327373f

typedef __bf16 bf16x8_t __attribute__((ext_vector_type(8)));
typedef float  f32x4_t  __attribute__((ext_vector_type(4)));

static __device__ __forceinline__ ushort f2bf(float f) {
    uint u = __float_as_uint(f);
    u = u + 0x7fffu + ((u >> 16) & 1u);   // RNE
    return (ushort)(u >> 16);
}
static __device__ __forceinline__ float bf2f(ushort b) {
    return __uint_as_float(((uint)b) << 16);
}

// ---------------------------------------------------------------------------
// Kernel 0: expand bias_table via rel_index into MFMA C-fragment order:
// biasF[h][tile=i*4+j][lane][r] so win_attn can init its QK accumulators
// directly from 16 coalesced float4 loads (bias rides in the MFMA C input).
// m = 16i + (lane>>4)*4 + r (key token), n = 16j + (lane&15) (query token).
// 8*16*64*4 floats = 128 KB; lives in the tail of d_out (dead until final GEMM).
// ---------------------------------------------------------------------------
__global__ __launch_bounds__(256) void bias_pre(
    const float* __restrict__ bt, const int* __restrict__ ri,
    float* __restrict__ biasF)
{
    int g = blockIdx.x * 256 + threadIdx.x;   // 0..32767
    int h    = g >> 12;
    int rem  = g & 4095;
    int tile = rem >> 8;            // i*4 + j
    int lane = (rem >> 2) & 63;
    int r    = rem & 3;
    int i = tile >> 2, j = tile & 3;
    int qd = lane >> 4, ln = lane & 15;
    int m = i * 16 + qd * 4 + r;
    int n = j * 16 + ln;
    biasF[g] = bt[ri[n * 64 + m] * 8 + h];
}

// ---------------------------------------------------------------------------
// Kernel 1: 1x1 conv, 64 -> 64 channels (fp32, VALU).
// ---------------------------------------------------------------------------
__global__ __launch_bounds__(256) void conv1x1_64(
    const float* __restrict__ X, const float* __restrict__ W,
    float* __restrict__ Y)
{
    int gp = blockIdx.x * 256 + threadIdx.x;
    int b  = gp >> 16;
    int p  = gp & 65535;
    const float* Xb = X + (size_t)b * 64 * HWN + p;
    float* Yb       = Y + (size_t)b * 64 * HWN + p;

    float xr[64];
#pragma unroll
    for (int c = 0; c < 64; c++) xr[c] = Xb[(size_t)c * HWN];

#pragma unroll 4
    for (int o = 0; o < 64; o++) {
        const float* Wr = W + o * 64;
        float acc = 0.f;
#pragma unroll
        for (int c = 0; c < 64; c++) acc = fmaf(Wr[c], xr[c], acc);
        Yb[(size_t)o * HWN] = acc;
    }
}

// ---------------------------------------------------------------------------
// Kernel 2: 256->256 channel GEMM via bf16 MFMA (unchanged).
// ---------------------------------------------------------------------------
template <typename XT, typename YT>
__global__ __launch_bounds__(256) void gemm256(
    const XT* __restrict__ X, const float* __restrict__ W, YT* __restrict__ Y)
{
    __shared__ ushort Al[128 * 72];   // [m][k], stride 72 bf16
    __shared__ ushort Bl[128 * 72];   // [n][k], swizzled 16B groups

    int b   = blockIdx.z;
    int oB  = blockIdx.y * 128;
    int pB  = blockIdx.x * 128;
    int tid = threadIdx.x;

    const XT* Xb = X + (size_t)b * 256 * HWN;
    YT*       Yb = Y + (size_t)b * 256 * HWN;

    int wv = tid >> 6, lane = tid & 63;
    int wm = (wv >> 1) * 64, wn = (wv & 1) * 64;
    int qd = lane >> 4, ln = lane & 15;

    int kgB = tid >> 4;
    int pgB = tid & 15;
    int p0  = pgB * 8;

    f32x4_t acc[4][4];
#pragma unroll
    for (int i = 0; i < 4; i++)
#pragma unroll
        for (int j = 0; j < 4; j++) acc[i][j] = {0.f, 0.f, 0.f, 0.f};

    for (int kc = 0; kc < 256; kc += 64) {
#pragma unroll
        for (int s = 0; s < 4; s++) {
            int u = tid + s * 256;
            int m = u >> 3, kg = u & 7;
            const float4* src = (const float4*)&W[(oB + m) * 256 + kc + kg * 8];
            float4 w0 = src[0], w1 = src[1];
            uint4 pk;
            pk.x = f2bf(w0.x) | ((uint)f2bf(w0.y) << 16);
            pk.y = f2bf(w0.z) | ((uint)f2bf(w0.w) << 16);
            pk.z = f2bf(w1.x) | ((uint)f2bf(w1.y) << 16);
            pk.w = f2bf(w1.z) | ((uint)f2bf(w1.w) << 16);
            *(uint4*)&Al[m * 72 + kg * 8] = pk;
        }
        ushort r[4][8];
#pragma unroll
        for (int i = 0; i < 4; i++) {
            int c = kc + kgB * 4 + i;
            if constexpr (sizeof(XT) == 4) {
                const float4* s = (const float4*)&Xb[(size_t)c * HWN + pB + p0];
                float4 x0 = s[0], x1 = s[1];
                r[i][0] = f2bf(x0.x); r[i][1] = f2bf(x0.y);
                r[i][2] = f2bf(x0.z); r[i][3] = f2bf(x0.w);
                r[i][4] = f2bf(x1.x); r[i][5] = f2bf(x1.y);
                r[i][6] = f2bf(x1.z); r[i][7] = f2bf(x1.w);
            } else {
                uint4 u = *(const uint4*)&Xb[(size_t)c * HWN + pB + p0];
                r[i][0] = u.x & 0xffff; r[i][1] = u.x >> 16;
                r[i][2] = u.y & 0xffff; r[i][3] = u.y >> 16;
                r[i][4] = u.z & 0xffff; r[i][5] = u.z >> 16;
                r[i][6] = u.w & 0xffff; r[i][7] = u.w >> 16;
            }
        }
        {
            int g   = kgB >> 1;
            int sub = (kgB & 1) * 4;
#pragma unroll
            for (int j = 0; j < 8; j++) {
                int n = p0 + j;
                ushort4 col = make_ushort4(r[0][j], r[1][j], r[2][j], r[3][j]);
                *(ushort4*)&Bl[n * 72 + ((g ^ (pgB & 7)) << 3) + sub] = col;
            }
        }
        __syncthreads();

#pragma unroll
        for (int ks = 0; ks < 2; ks++) {
            bf16x8_t af[4], bf[4];
#pragma unroll
            for (int i = 0; i < 4; i++)
                af[i] = *(const bf16x8_t*)&Al[(wm + i * 16 + ln) * 72 + ks * 32 + qd * 8];
#pragma unroll
            for (int j = 0; j < 4; j++) {
                int n = wn + j * 16 + ln;
                int g = ks * 4 + qd;
                bf[j] = *(const bf16x8_t*)&Bl[n * 72 + ((g ^ ((n >> 3) & 7)) << 3)];
            }
#pragma unroll
            for (int i = 0; i < 4; i++)
#pragma unroll
                for (int j = 0; j < 4; j++)
                    acc[i][j] = __builtin_amdgcn_mfma_f32_16x16x32_bf16(
                        af[i], bf[j], acc[i][j], 0, 0, 0);
        }
        __syncthreads();
    }

#pragma unroll
    for (int i = 0; i < 4; i++) {
#pragma unroll
        for (int j = 0; j < 4; j++) {
#pragma unroll
            for (int rr = 0; rr < 4; rr++) {
                int o = oB + wm + i * 16 + qd * 4 + rr;
                int p = pB + wn + j * 16 + ln;
                if constexpr (sizeof(YT) == 4)
                    Yb[(size_t)o * HWN + p] = acc[i][j][rr];
                else
                    Yb[(size_t)o * HWN + p] = f2bf(acc[i][j][rr]);
            }
        }
    }
}

// ---------------------------------------------------------------------------
// Kernel 3: windowed attention v3.  One wave per (window, head).
// R3: QK^T moved to the MFMA pipe (was 512 broadcast ds_read_b32 + 640 VALU
// FMAs + 64 bias loads per thread -> MfmaUtil 1.5%, dur 111us).
//   S^T = K.Q^T via 16x mfma_16x16x32_bf16, k-slots = [khi|khi|klo]x[qhi|qlo|qhi]
//   (error-compensated split ~ f32 precision); scale folded into Q;
//   bias pre-packed in C-fragment order rides in as the MFMA C initializer.
//   Softmax on S^T: 15 in-lane fmax + 2 shfl_xor per column group.
//   ql/kq rows: stride 40 ushorts -> optimal 8-access/bank for all b128 ops.
// PV unchanged (P->LDS bf16 rows, V B-frags direct from global).
// OUT may alias VP (reads precede writes within the block).
// ---------------------------------------------------------------------------
__global__ __launch_bounds__(64, 4) void win_attn(
    const float* __restrict__ QP, const float* __restrict__ KP,
    const ushort* VP, ushort* OUT, const float* __restrict__ biasF)
{
    __shared__ char smem[10240];
    ushort* ql = (ushort*)smem;                  // [64][40] phase 1 (Q split)
    ushort* kq = (ushort*)(smem + 5120);         // [64][40] phase 1 (K split)
    ushort* pl = (ushort*)smem;                  // [64][72] phase 2 (P bf16)
    float*  ol = (float*)smem;                   // [64][36] phase 3 (O f32)

    int bx   = blockIdx.x;
    int head = bx & 7;
    int win  = bx >> 3;
    int wc   = win & 31;
    int wr   = (win >> 5) & 31;
    int b    = win >> 10;

    int n   = threadIdx.x;
    int ws1 = n >> 3, ws2 = n & 7;
    int pos = (wr * 8 + ws1) * 256 + wc * 8 + ws2;

    const float*  qb = QP + ((size_t)(b * 64 + head * 8)) * HWN + pos;
    const float*  kb = KP + ((size_t)(b * 64 + head * 8)) * HWN + pos;
    const ushort* vbase = VP + ((size_t)(b * 256 + head * 32)) * HWN
                             + (size_t)(wr * 8) * 256 + wc * 8;
    ushort*       ob = OUT + ((size_t)(b * 256 + head * 32)) * HWN + pos;

    // ---- stage q (scaled, hi/lo split) and k (hi/lo split) as bf16 rows ----
    uint qh[4], qlw[4], kh[4], klw[4];
#pragma unroll
    for (int d = 0; d < 4; d++) {
        float q0 = qb[(size_t)(2 * d)     * HWN] * SCALE;
        float q1 = qb[(size_t)(2 * d + 1) * HWN] * SCALE;
        ushort qh0 = f2bf(q0), qh1 = f2bf(q1);
        ushort ql0 = f2bf(q0 - bf2f(qh0)), ql1 = f2bf(q1 - bf2f(qh1));
        qh[d]  = (uint)qh0 | ((uint)qh1 << 16);
        qlw[d] = (uint)ql0 | ((uint)ql1 << 16);
        float k0 = kb[(size_t)(2 * d)     * HWN];
        float k1 = kb[(size_t)(2 * d + 1) * HWN];
        ushort kh0 = f2bf(k0), kh1 = f2bf(k1);
        ushort kl0 = f2bf(k0 - bf2f(kh0)), kl1 = f2bf(k1 - bf2f(kh1));
        kh[d]  = (uint)kh0 | ((uint)kh1 << 16);
        klw[d] = (uint)kl0 | ((uint)kl1 << 16);
    }
    uint4 z4 = make_uint4(0u, 0u, 0u, 0u);
    uint4 qhv = make_uint4(qh[0], qh[1], qh[2], qh[3]);
    uint4 qlv = make_uint4(qlw[0], qlw[1], qlw[2], qlw[3]);
    uint4 khv = make_uint4(kh[0], kh[1], kh[2], kh[3]);
    uint4 klv = make_uint4(klw[0], klw[1], klw[2], klw[3]);
    // Q row: [qhi | qlo | qhi | 0]; K row: [khi | khi | klo | 0]
    *(uint4*)&ql[n * 40 +  0] = qhv;
    *(uint4*)&ql[n * 40 +  8] = qlv;
    *(uint4*)&ql[n * 40 + 16] = qhv;
    *(uint4*)&ql[n * 40 + 24] = z4;
    *(uint4*)&kq[n * 40 +  0] = khv;
    *(uint4*)&kq[n * 40 +  8] = khv;
    *(uint4*)&kq[n * 40 + 16] = klv;
    *(uint4*)&kq[n * 40 + 24] = z4;
    __syncthreads();

    int ln = n & 15, qd = n >> 4;

    // ---- S^T = K.Q^T + bias via MFMA (C init = bias fragment) ----
    f32x4_t sacc[4][4];
    const float* bfr = biasF + (size_t)head * 4096;   // [tile][lane][r]
#pragma unroll
    for (int i = 0; i < 4; i++)
#pragma unroll
        for (int j = 0; j < 4; j++)
            sacc[i][j] = *(const f32x4_t*)&bfr[((i * 4 + j) * 64 + n) * 4];

    bf16x8_t kf[4];
#pragma unroll
    for (int i = 0; i < 4; i++)
        kf[i] = *(const bf16x8_t*)&kq[(16 * i + ln) * 40 + qd * 8];
#pragma unroll
    for (int j = 0; j < 4; j++) {
        bf16x8_t qf = *(const bf16x8_t*)&ql[(16 * j + ln) * 40 + qd * 8];
#pragma unroll
        for (int i = 0; i < 4; i++)
            sacc[i][j] = __builtin_amdgcn_mfma_f32_16x16x32_bf16(
                kf[i], qf, sacc[i][j], 0, 0, 0);
    }
    // lane holds S^T[m][n'] + bias, m = 16i + qd*4 + r, n' = 16j + ln

    // ---- softmax over m: 15 in-lane fmax/adds + shfl_xor(16,32) per j ----
    float rs[4];
#pragma unroll
    for (int j = 0; j < 4; j++) {
        float m0 = sacc[0][j][0];
#pragma unroll
        for (int i = 0; i < 4; i++)
#pragma unroll
            for (int r = 0; r < 4; r++) m0 = fmaxf(m0, sacc[i][j][r]);
        m0 = fmaxf(m0, __shfl_xor(m0, 16));
        m0 = fmaxf(m0, __shfl_xor(m0, 32));
        float s0 = 0.f;
#pragma unroll
        for (int i = 0; i < 4; i++)
#pragma unroll
            for (int r = 0; r < 4; r++) {
                float e = __expf(sacc[i][j][r] - m0);
                sacc[i][j][r] = e;
                s0 += e;
            }
        s0 += __shfl_xor(s0, 16);
        s0 += __shfl_xor(s0, 32);
        rs[j] = 1.f / s0;
    }

    __syncthreads();   // ql/kq fully consumed; reuse smem as pl

    // ---- P^T -> pl[n'][m] bf16 (16x ds_write_b64) ----
#pragma unroll
    for (int i = 0; i < 4; i++)
#pragma unroll
        for (int j = 0; j < 4; j++) {
            uint lo = (uint)f2bf(sacc[i][j][0] * rs[j])
                    | ((uint)f2bf(sacc[i][j][1] * rs[j]) << 16);
            uint hi = (uint)f2bf(sacc[i][j][2] * rs[j])
                    | ((uint)f2bf(sacc[i][j][3] * rs[j]) << 16);
            *(uint2*)&pl[(16 * j + ln) * 72 + 16 * i + qd * 4] = make_uint2(lo, hi);
        }
    __syncthreads();

    // ---- PV via MFMA: O[n][d] = sum_m P[n][m] V[m][d] ----
    f32x4_t acc[4][2];
#pragma unroll
    for (int i = 0; i < 4; i++)
#pragma unroll
        for (int j = 0; j < 2; j++) acc[i][j] = {0.f, 0.f, 0.f, 0.f};

#pragma unroll
    for (int kc = 0; kc < 2; kc++) {
        bf16x8_t af[4], bfv[2];
#pragma unroll
        for (int i = 0; i < 4; i++)
            af[i] = *(const bf16x8_t*)&pl[(16 * i + ln) * 72 + kc * 32 + qd * 8];
#pragma unroll
        for (int j = 0; j < 2; j++) {
            // B[d=16j+ln][k=m]: 8 consecutive tokens, contiguous 16B in global
            const ushort* vp8 = vbase + (size_t)(16 * j + ln) * HWN
                                      + (kc * 4 + qd) * 256;
            uint4 u = *(const uint4*)vp8;
            bfv[j] = *(const bf16x8_t*)&u;
        }
#pragma unroll
        for (int i = 0; i < 4; i++)
#pragma unroll
            for (int j = 0; j < 2; j++)
                acc[i][j] = __builtin_amdgcn_mfma_f32_16x16x32_bf16(
                    af[i], bfv[j], acc[i][j], 0, 0, 0);
    }
    __syncthreads();   // pl fully consumed; reuse smem as ol

    // ---- C-layout -> LDS -> per-lane rows, coalesced stores ----
#pragma unroll
    for (int i = 0; i < 4; i++)
#pragma unroll
        for (int j = 0; j < 2; j++)
#pragma unroll
            for (int r = 0; r < 4; r++)
                ol[(16 * i + qd * 4 + r) * 36 + j * 16 + ln] = acc[i][j][r];
    __syncthreads();

#pragma unroll
    for (int c = 0; c < 8; c++) {
        float4 o4 = *(const float4*)&ol[n * 36 + c * 4];
        ob[(size_t)(c * 4 + 0) * HWN] = f2bf(o4.x);
        ob[(size_t)(c * 4 + 1) * HWN] = f2bf(o4.y);
        ob[(size_t)(c * 4 + 2) * HWN] = f2bf(o4.z);
        ob[(size_t)(c * 4 + 3) * HWN] = f2bf(o4.w);
    }
}

// ---------------------------------------------------------------------------
// Kernel 4: reflect-pad + 8x8 depthwise conv + BN.  bf16 in/out, fp32 math.
// R4 register blocking: each thread computes a 4-wide x 8-tall strip.
// ---------------------------------------------------------------------------
__global__ __launch_bounds__(256) void dwconv_bn(
    const ushort* __restrict__ A, const float* __restrict__ DW,
    const float* __restrict__ gamma, const float* __restrict__ beta,
    const float* __restrict__ mean, const float* __restrict__ var,
    ushort* __restrict__ O)
{
    __shared__ float til[71 * 136];

    int c  = blockIdx.y;
    int b  = blockIdx.z;
    int tX = (blockIdx.x & 1) * 128;
    int tY = (blockIdx.x >> 1) * 64;
    int tid = threadIdx.x;

    const ushort* Ab = A + ((size_t)(b * 256 + c)) * HWN;

    // ---- tile load: 71 rows x 17 ushort8-chunks (136 cols incl. slack) ----
    for (int li = tid; li < 71 * 17; li += 256) {
        int yr = li / 17;
        int ck = li - yr * 17;
        int iy = tY - 3 + yr;
        int xb = tX - 3 + ck * 8;
        float vals[8];
        if (iy < 0 || iy > 256) {
#pragma unroll
            for (int e = 0; e < 8; e++) vals[e] = 0.f;
        } else {
            int sy = (iy == 256) ? 254 : iy;
            const ushort* row = Ab + sy * 256;
            if (xb >= 0 && xb + 7 <= 255) {
                uint4 u = *(const uint4*)&row[xb];
                vals[0] = bf2f(u.x & 0xffff); vals[1] = bf2f(u.x >> 16);
                vals[2] = bf2f(u.y & 0xffff); vals[3] = bf2f(u.y >> 16);
                vals[4] = bf2f(u.z & 0xffff); vals[5] = bf2f(u.z >> 16);
                vals[6] = bf2f(u.w & 0xffff); vals[7] = bf2f(u.w >> 16);
            } else {
#pragma unroll
                for (int e = 0; e < 8; e++) {
                    int ix = xb + e;
                    if (ix < 0 || ix > 256) vals[e] = 0.f;
                    else vals[e] = bf2f(row[(ix == 256) ? 254 : ix]);
                }
            }
        }
        float4 lo = {vals[0], vals[1], vals[2], vals[3]};
        float4 hi = {vals[4], vals[5], vals[6], vals[7]};
        *(float4*)&til[yr * 136 + ck * 8]     = lo;
        *(float4*)&til[yr * 136 + ck * 8 + 4] = hi;
    }

    // ---- weights: uniform address -> scalar loads ----
    float w[64];
#pragma unroll
    for (int i = 0; i < 16; i++)
        *(float4*)&w[i * 4] = *(const float4*)&DW[c * 64 + i * 4];

    __syncthreads();

    float inv = gamma[c] * rsqrtf(var[c] + 1e-5f);
    float add = fmaf(-mean[c], inv, beta[c]);

    int xg = tid & 31;       // 32 x-groups * 4 wide = 128
    int yg = tid >> 5;       // 8  y-groups * 8 tall = 64
    int xo = xg * 4;
    int yb = yg * 8;

    float acc[8][4];
#pragma unroll
    for (int j = 0; j < 8; j++)
#pragma unroll
        for (int p = 0; p < 4; p++) acc[j][p] = 0.f;

#pragma unroll
    for (int r = 0; r < 15; r++) {
        const float4* rp = (const float4*)&til[(yb + r) * 136 + xo];
        float4 q0 = rp[0], q1 = rp[1], q2 = rp[2];
        float row[12] = {q0.x, q0.y, q0.z, q0.w,
                         q1.x, q1.y, q1.z, q1.w,
                         q2.x, q2.y, q2.z, q2.w};   // row[11] slack, unused
        int jlo = (r - 7 < 0) ? 0 : r - 7;
        int jhi = (r < 7) ? r : 7;
#pragma unroll
        for (int j = jlo; j <= jhi; j++) {
            const float* wr = &w[(r - j) * 8];
#pragma unroll
            for (int kx = 0; kx < 8; kx++) {
                float wt = wr[kx];
                acc[j][0] = fmaf(row[kx + 0], wt, acc[j][0]);
                acc[j][1] = fmaf(row[kx + 1], wt, acc[j][1]);
                acc[j][2] = fmaf(row[kx + 2], wt, acc[j][2]);
                acc[j][3] = fmaf(row[kx + 3], wt, acc[j][3]);
            }
        }
    }

    ushort* Ob = O + ((size_t)(b * 256 + c)) * HWN;
#pragma unroll
    for (int j = 0; j < 8; j++) {
        ushort4 r4 = make_ushort4(
            f2bf(fmaf(acc[j][0], inv, add)), f2bf(fmaf(acc[j][1], inv, add)),
            f2bf(fmaf(acc[j][2], inv, add)), f2bf(fmaf(acc[j][3], inv, add)));
        *(ushort4*)&Ob[(tY + yb + j) * 256 + tX + xo] = r4;
    }
}

// ---------------------------------------------------------------------------
// Workspace (192 MiB): qp f32 | kp f32 | vp bf16 (aliased by attn out) | dwo.
// biasF (128 KB) lives in the tail of d_out — dead until the final GEMM,
// which overwrites it after win_attn has consumed it.
// ---------------------------------------------------------------------------
extern "C" void kernel_launch(void* const* d_in, const int* in_sizes, int n_in,
                              void* d_out, int out_size, void* d_ws, size_t ws_size,
                              hipStream_t stream)
{
    (void)in_sizes; (void)n_in; (void)ws_size;

    const float* q    = (const float*)d_in[0];
    const float* v    = (const float*)d_in[1];
    const float* Wq   = (const float*)d_in[2];
    const float* Wk   = (const float*)d_in[3];
    const float* Wv   = (const float*)d_in[4];
    const float* bt   = (const float*)d_in[5];
    const float* dw   = (const float*)d_in[6];
    const float* gam  = (const float*)d_in[7];
    const float* bet  = (const float*)d_in[8];
    const float* mean = (const float*)d_in[9];
    const float* var  = (const float*)d_in[10];
    const float* pw   = (const float*)d_in[11];
    const int*   ri   = (const int*)d_in[12];
    float* out = (float*)d_out;

    float*  qp  = (float*)d_ws;
    float*  kp  = qp + (size_t)2 * 64 * HWN;
    ushort* vp  = (ushort*)(kp + (size_t)2 * 64 * HWN);
    ushort* ao  = vp;                          // alias, see win_attn comment
    ushort* dwo = vp + (size_t)2 * 256 * HWN;
    float*  biasF = out + (size_t)out_size - 32768;

    bias_pre<<<128, 256, 0, stream>>>(bt, ri, biasF);
    conv1x1_64<<<512, 256, 0, stream>>>(q, Wq, qp);
    conv1x1_64<<<512, 256, 0, stream>>>(qp, Wk, kp);
    gemm256<float, ushort><<<dim3(512, 2, 2), 256, 0, stream>>>(v, Wv, vp);
    win_attn<<<16384, 64, 0, stream>>>(qp, kp, vp, ao, biasF);
    dwconv_bn<<<dim3(8, 256, 2), 256, 0, stream>>>(ao, dw, gam, bet, mean, var, dwo);
    gemm256<ushort, float><<<dim3(512, 2, 2), 256, 0, stream>>>(dwo, pw, out);
}

// Round 4
// 618.575 us; speedup vs baseline: 1.1965x; 1.0479x over previous
//
#include <hip/hip_runtime.h>
#include <cstddef>

#define HWN 65536              // 256*256
#define SCALE 0.35355339059327373f

typedef __bf16 bf16x8_t __attribute__((ext_vector_type(8)));
typedef float  f32x4_t  __attribute__((ext_vector_type(4)));

static __device__ __forceinline__ ushort f2bf(float f) {
    uint u = __float_as_uint(f);
    u = u + 0x7fffu + ((u >> 16) & 1u);   // RNE
    return (ushort)(u >> 16);
}
static __device__ __forceinline__ float bf2f(ushort b) {
    return __uint_as_float(((uint)b) << 16);
}

// ---------------------------------------------------------------------------
// Kernel 0: expand bias_table via rel_index into MFMA C-fragment order:
// biasF[h][tile=i*4+j][lane][r] so win_attn can init its QK accumulators
// directly from 16 coalesced float4 loads (bias rides in the MFMA C input).
// m = 16i + (lane>>4)*4 + r (key token), n = 16j + (lane&15) (query token).
// 8*16*64*4 floats = 128 KB; lives in the tail of d_out (dead until final GEMM).
// ---------------------------------------------------------------------------
__global__ __launch_bounds__(256) void bias_pre(
    const float* __restrict__ bt, const int* __restrict__ ri,
    float* __restrict__ biasF)
{
    int g = blockIdx.x * 256 + threadIdx.x;   // 0..32767
    int h    = g >> 12;
    int rem  = g & 4095;
    int tile = rem >> 8;            // i*4 + j
    int lane = (rem >> 2) & 63;
    int r    = rem & 3;
    int i = tile >> 2, j = tile & 3;
    int qd = lane >> 4, ln = lane & 15;
    int m = i * 16 + qd * 4 + r;
    int n = j * 16 + ln;
    biasF[g] = bt[ri[n * 64 + m] * 8 + h];
}

// ---------------------------------------------------------------------------
// Kernel 1: 1x1 conv, 64 -> 64 channels (fp32, VALU).
// ---------------------------------------------------------------------------
__global__ __launch_bounds__(256) void conv1x1_64(
    const float* __restrict__ X, const float* __restrict__ W,
    float* __restrict__ Y)
{
    int gp = blockIdx.x * 256 + threadIdx.x;
    int b  = gp >> 16;
    int p  = gp & 65535;
    const float* Xb = X + (size_t)b * 64 * HWN + p;
    float* Yb       = Y + (size_t)b * 64 * HWN + p;

    float xr[64];
#pragma unroll
    for (int c = 0; c < 64; c++) xr[c] = Xb[(size_t)c * HWN];

#pragma unroll 4
    for (int o = 0; o < 64; o++) {
        const float* Wr = W + o * 64;
        float acc = 0.f;
#pragma unroll
        for (int c = 0; c < 64; c++) acc = fmaf(Wr[c], xr[c], acc);
        Yb[(size_t)o * HWN] = acc;
    }
}

// ---------------------------------------------------------------------------
// Kernel 2: 256->256 channel GEMM via bf16 MFMA (unchanged).
// ---------------------------------------------------------------------------
template <typename XT, typename YT>
__global__ __launch_bounds__(256) void gemm256(
    const XT* __restrict__ X, const float* __restrict__ W, YT* __restrict__ Y)
{
    __shared__ ushort Al[128 * 72];   // [m][k], stride 72 bf16
    __shared__ ushort Bl[128 * 72];   // [n][k], swizzled 16B groups

    int b   = blockIdx.z;
    int oB  = blockIdx.y * 128;
    int pB  = blockIdx.x * 128;
    int tid = threadIdx.x;

    const XT* Xb = X + (size_t)b * 256 * HWN;
    YT*       Yb = Y + (size_t)b * 256 * HWN;

    int wv = tid >> 6, lane = tid & 63;
    int wm = (wv >> 1) * 64, wn = (wv & 1) * 64;
    int qd = lane >> 4, ln = lane & 15;

    int kgB = tid >> 4;
    int pgB = tid & 15;
    int p0  = pgB * 8;

    f32x4_t acc[4][4];
#pragma unroll
    for (int i = 0; i < 4; i++)
#pragma unroll
        for (int j = 0; j < 4; j++) acc[i][j] = {0.f, 0.f, 0.f, 0.f};

    for (int kc = 0; kc < 256; kc += 64) {
#pragma unroll
        for (int s = 0; s < 4; s++) {
            int u = tid + s * 256;
            int m = u >> 3, kg = u & 7;
            const float4* src = (const float4*)&W[(oB + m) * 256 + kc + kg * 8];
            float4 w0 = src[0], w1 = src[1];
            uint4 pk;
            pk.x = f2bf(w0.x) | ((uint)f2bf(w0.y) << 16);
            pk.y = f2bf(w0.z) | ((uint)f2bf(w0.w) << 16);
            pk.z = f2bf(w1.x) | ((uint)f2bf(w1.y) << 16);
            pk.w = f2bf(w1.z) | ((uint)f2bf(w1.w) << 16);
            *(uint4*)&Al[m * 72 + kg * 8] = pk;
        }
        ushort r[4][8];
#pragma unroll
        for (int i = 0; i < 4; i++) {
            int c = kc + kgB * 4 + i;
            if constexpr (sizeof(XT) == 4) {
                const float4* s = (const float4*)&Xb[(size_t)c * HWN + pB + p0];
                float4 x0 = s[0], x1 = s[1];
                r[i][0] = f2bf(x0.x); r[i][1] = f2bf(x0.y);
                r[i][2] = f2bf(x0.z); r[i][3] = f2bf(x0.w);
                r[i][4] = f2bf(x1.x); r[i][5] = f2bf(x1.y);
                r[i][6] = f2bf(x1.z); r[i][7] = f2bf(x1.w);
            } else {
                uint4 u = *(const uint4*)&Xb[(size_t)c * HWN + pB + p0];
                r[i][0] = u.x & 0xffff; r[i][1] = u.x >> 16;
                r[i][2] = u.y & 0xffff; r[i][3] = u.y >> 16;
                r[i][4] = u.z & 0xffff; r[i][5] = u.z >> 16;
                r[i][6] = u.w & 0xffff; r[i][7] = u.w >> 16;
            }
        }
        {
            int g   = kgB >> 1;
            int sub = (kgB & 1) * 4;
#pragma unroll
            for (int j = 0; j < 8; j++) {
                int n = p0 + j;
                ushort4 col = make_ushort4(r[0][j], r[1][j], r[2][j], r[3][j]);
                *(ushort4*)&Bl[n * 72 + ((g ^ (pgB & 7)) << 3) + sub] = col;
            }
        }
        __syncthreads();

#pragma unroll
        for (int ks = 0; ks < 2; ks++) {
            bf16x8_t af[4], bf[4];
#pragma unroll
            for (int i = 0; i < 4; i++)
                af[i] = *(const bf16x8_t*)&Al[(wm + i * 16 + ln) * 72 + ks * 32 + qd * 8];
#pragma unroll
            for (int j = 0; j < 4; j++) {
                int n = wn + j * 16 + ln;
                int g = ks * 4 + qd;
                bf[j] = *(const bf16x8_t*)&Bl[n * 72 + ((g ^ ((n >> 3) & 7)) << 3)];
            }
#pragma unroll
            for (int i = 0; i < 4; i++)
#pragma unroll
                for (int j = 0; j < 4; j++)
                    acc[i][j] = __builtin_amdgcn_mfma_f32_16x16x32_bf16(
                        af[i], bf[j], acc[i][j], 0, 0, 0);
        }
        __syncthreads();
    }

#pragma unroll
    for (int i = 0; i < 4; i++) {
#pragma unroll
        for (int j = 0; j < 4; j++) {
#pragma unroll
            for (int rr = 0; rr < 4; rr++) {
                int o = oB + wm + i * 16 + qd * 4 + rr;
                int p = pB + wn + j * 16 + ln;
                if constexpr (sizeof(YT) == 4)
                    Yb[(size_t)o * HWN + p] = acc[i][j][rr];
                else
                    Yb[(size_t)o * HWN + p] = f2bf(acc[i][j][rr]);
            }
        }
    }
}

// ---------------------------------------------------------------------------
// Kernel 3: windowed attention v3.  One wave per (window, head).
// S^T = K.Q^T via MFMA (error-compensated bf16 split, bias rides in C);
// softmax mostly in-lane; PV via MFMA.  OUT may alias VP.
// ---------------------------------------------------------------------------
__global__ __launch_bounds__(64, 4) void win_attn(
    const float* __restrict__ QP, const float* __restrict__ KP,
    const ushort* VP, ushort* OUT, const float* __restrict__ biasF)
{
    __shared__ char smem[10240];
    ushort* ql = (ushort*)smem;                  // [64][40] phase 1 (Q split)
    ushort* kq = (ushort*)(smem + 5120);         // [64][40] phase 1 (K split)
    ushort* pl = (ushort*)smem;                  // [64][72] phase 2 (P bf16)
    float*  ol = (float*)smem;                   // [64][36] phase 3 (O f32)

    int bx   = blockIdx.x;
    int head = bx & 7;
    int win  = bx >> 3;
    int wc   = win & 31;
    int wr   = (win >> 5) & 31;
    int b    = win >> 10;

    int n   = threadIdx.x;
    int ws1 = n >> 3, ws2 = n & 7;
    int pos = (wr * 8 + ws1) * 256 + wc * 8 + ws2;

    const float*  qb = QP + ((size_t)(b * 64 + head * 8)) * HWN + pos;
    const float*  kb = KP + ((size_t)(b * 64 + head * 8)) * HWN + pos;
    const ushort* vbase = VP + ((size_t)(b * 256 + head * 32)) * HWN
                             + (size_t)(wr * 8) * 256 + wc * 8;
    ushort*       ob = OUT + ((size_t)(b * 256 + head * 32)) * HWN + pos;

    // ---- stage q (scaled, hi/lo split) and k (hi/lo split) as bf16 rows ----
    uint qh[4], qlw[4], kh[4], klw[4];
#pragma unroll
    for (int d = 0; d < 4; d++) {
        float q0 = qb[(size_t)(2 * d)     * HWN] * SCALE;
        float q1 = qb[(size_t)(2 * d + 1) * HWN] * SCALE;
        ushort qh0 = f2bf(q0), qh1 = f2bf(q1);
        ushort ql0 = f2bf(q0 - bf2f(qh0)), ql1 = f2bf(q1 - bf2f(qh1));
        qh[d]  = (uint)qh0 | ((uint)qh1 << 16);
        qlw[d] = (uint)ql0 | ((uint)ql1 << 16);
        float k0 = kb[(size_t)(2 * d)     * HWN];
        float k1 = kb[(size_t)(2 * d + 1) * HWN];
        ushort kh0 = f2bf(k0), kh1 = f2bf(k1);
        ushort kl0 = f2bf(k0 - bf2f(kh0)), kl1 = f2bf(k1 - bf2f(kh1));
        kh[d]  = (uint)kh0 | ((uint)kh1 << 16);
        klw[d] = (uint)kl0 | ((uint)kl1 << 16);
    }
    uint4 z4 = make_uint4(0u, 0u, 0u, 0u);
    uint4 qhv = make_uint4(qh[0], qh[1], qh[2], qh[3]);
    uint4 qlv = make_uint4(qlw[0], qlw[1], qlw[2], qlw[3]);
    uint4 khv = make_uint4(kh[0], kh[1], kh[2], kh[3]);
    uint4 klv = make_uint4(klw[0], klw[1], klw[2], klw[3]);
    // Q row: [qhi | qlo | qhi | 0]; K row: [khi | khi | klo | 0]
    *(uint4*)&ql[n * 40 +  0] = qhv;
    *(uint4*)&ql[n * 40 +  8] = qlv;
    *(uint4*)&ql[n * 40 + 16] = qhv;
    *(uint4*)&ql[n * 40 + 24] = z4;
    *(uint4*)&kq[n * 40 +  0] = khv;
    *(uint4*)&kq[n * 40 +  8] = khv;
    *(uint4*)&kq[n * 40 + 16] = klv;
    *(uint4*)&kq[n * 40 + 24] = z4;
    __syncthreads();

    int ln = n & 15, qd = n >> 4;

    // ---- S^T = K.Q^T + bias via MFMA (C init = bias fragment) ----
    f32x4_t sacc[4][4];
    const float* bfr = biasF + (size_t)head * 4096;   // [tile][lane][r]
#pragma unroll
    for (int i = 0; i < 4; i++)
#pragma unroll
        for (int j = 0; j < 4; j++)
            sacc[i][j] = *(const f32x4_t*)&bfr[((i * 4 + j) * 64 + n) * 4];

    bf16x8_t kf[4];
#pragma unroll
    for (int i = 0; i < 4; i++)
        kf[i] = *(const bf16x8_t*)&kq[(16 * i + ln) * 40 + qd * 8];
#pragma unroll
    for (int j = 0; j < 4; j++) {
        bf16x8_t qf = *(const bf16x8_t*)&ql[(16 * j + ln) * 40 + qd * 8];
#pragma unroll
        for (int i = 0; i < 4; i++)
            sacc[i][j] = __builtin_amdgcn_mfma_f32_16x16x32_bf16(
                kf[i], qf, sacc[i][j], 0, 0, 0);
    }
    // lane holds S^T[m][n'] + bias, m = 16i + qd*4 + r, n' = 16j + ln

    // ---- softmax over m: 15 in-lane fmax/adds + shfl_xor(16,32) per j ----
    float rs[4];
#pragma unroll
    for (int j = 0; j < 4; j++) {
        float m0 = sacc[0][j][0];
#pragma unroll
        for (int i = 0; i < 4; i++)
#pragma unroll
            for (int r = 0; r < 4; r++) m0 = fmaxf(m0, sacc[i][j][r]);
        m0 = fmaxf(m0, __shfl_xor(m0, 16));
        m0 = fmaxf(m0, __shfl_xor(m0, 32));
        float s0 = 0.f;
#pragma unroll
        for (int i = 0; i < 4; i++)
#pragma unroll
            for (int r = 0; r < 4; r++) {
                float e = __expf(sacc[i][j][r] - m0);
                sacc[i][j][r] = e;
                s0 += e;
            }
        s0 += __shfl_xor(s0, 16);
        s0 += __shfl_xor(s0, 32);
        rs[j] = 1.f / s0;
    }

    __syncthreads();   // ql/kq fully consumed; reuse smem as pl

    // ---- P^T -> pl[n'][m] bf16 (16x ds_write_b64) ----
#pragma unroll
    for (int i = 0; i < 4; i++)
#pragma unroll
        for (int j = 0; j < 4; j++) {
            uint lo = (uint)f2bf(sacc[i][j][0] * rs[j])
                    | ((uint)f2bf(sacc[i][j][1] * rs[j]) << 16);
            uint hi = (uint)f2bf(sacc[i][j][2] * rs[j])
                    | ((uint)f2bf(sacc[i][j][3] * rs[j]) << 16);
            *(uint2*)&pl[(16 * j + ln) * 72 + 16 * i + qd * 4] = make_uint2(lo, hi);
        }
    __syncthreads();

    // ---- PV via MFMA: O[n][d] = sum_m P[n][m] V[m][d] ----
    f32x4_t acc[4][2];
#pragma unroll
    for (int i = 0; i < 4; i++)
#pragma unroll
        for (int j = 0; j < 2; j++) acc[i][j] = {0.f, 0.f, 0.f, 0.f};

#pragma unroll
    for (int kc = 0; kc < 2; kc++) {
        bf16x8_t af[4], bfv[2];
#pragma unroll
        for (int i = 0; i < 4; i++)
            af[i] = *(const bf16x8_t*)&pl[(16 * i + ln) * 72 + kc * 32 + qd * 8];
#pragma unroll
        for (int j = 0; j < 2; j++) {
            // B[d=16j+ln][k=m]: 8 consecutive tokens, contiguous 16B in global
            const ushort* vp8 = vbase + (size_t)(16 * j + ln) * HWN
                                      + (kc * 4 + qd) * 256;
            uint4 u = *(const uint4*)vp8;
            bfv[j] = *(const bf16x8_t*)&u;
        }
#pragma unroll
        for (int i = 0; i < 4; i++)
#pragma unroll
            for (int j = 0; j < 2; j++)
                acc[i][j] = __builtin_amdgcn_mfma_f32_16x16x32_bf16(
                    af[i], bfv[j], acc[i][j], 0, 0, 0);
    }
    __syncthreads();   // pl fully consumed; reuse smem as ol

    // ---- C-layout -> LDS -> per-lane rows, coalesced stores ----
#pragma unroll
    for (int i = 0; i < 4; i++)
#pragma unroll
        for (int j = 0; j < 2; j++)
#pragma unroll
            for (int r = 0; r < 4; r++)
                ol[(16 * i + qd * 4 + r) * 36 + j * 16 + ln] = acc[i][j][r];
    __syncthreads();

#pragma unroll
    for (int c = 0; c < 8; c++) {
        float4 o4 = *(const float4*)&ol[n * 36 + c * 4];
        ob[(size_t)(c * 4 + 0) * HWN] = f2bf(o4.x);
        ob[(size_t)(c * 4 + 1) * HWN] = f2bf(o4.y);
        ob[(size_t)(c * 4 + 2) * HWN] = f2bf(o4.z);
        ob[(size_t)(c * 4 + 3) * HWN] = f2bf(o4.w);
    }
}

// ---------------------------------------------------------------------------
// Kernel 4: reflect-pad + 8x8 depthwise conv + BN.  bf16 in/out, fp32 math.
// R4b: bf16 LDS tile + 8-wide x 4-tall thread strips.
//   R3 post-mortem: 100us with occupancy 27% (38.9KB f32 LDS -> ~2 blocks/CU)
//   and 45 ds_read_b128 per 32 outputs.  Now: LDS 21.2KB bf16 (no loader
//   conversions; interior chunks are raw uint4 copies), 33 ds_read_b128 per
//   32 outputs, all accesses 16B-aligned, launch_bounds(256,5) -> ~5 blocks/CU.
//   Tile: 256 wide x 32 tall; til[39][272] bf16, LDS col cc = ix + 8
//   (ix in [-8,263]; <0 and >256 are zero-pad, ix==256 reflects to 254).
// ---------------------------------------------------------------------------
__global__ __launch_bounds__(256, 5) void dwconv_bn(
    const ushort* __restrict__ A, const float* __restrict__ DW,
    const float* __restrict__ gamma, const float* __restrict__ beta,
    const float* __restrict__ mean, const float* __restrict__ var,
    ushort* __restrict__ O)
{
    __shared__ ushort til[39 * 272];

    int c  = blockIdx.y;
    int b  = blockIdx.z;
    int tY = blockIdx.x * 32;
    int tid = threadIdx.x;

    const ushort* Ab = A + ((size_t)(b * 256 + c)) * HWN;

    // ---- tile load: 39 rows x 34 uint4-chunks of 8 bf16 ----
    for (int li = tid; li < 39 * 34; li += 256) {
        int yr = li / 34;
        int ck = li - yr * 34;
        int iy = tY - 3 + yr;
        uint4 u = make_uint4(0u, 0u, 0u, 0u);
        if (iy >= 0 && iy <= 256) {
            int sy = (iy == 256) ? 254 : iy;
            const ushort* row = Ab + sy * 256;
            if (ck >= 1 && ck <= 32) {
                u = *(const uint4*)&row[ck * 8 - 8];   // ix = 8ck-8..8ck-1, aligned
            } else if (ck == 33) {
                u.x = (uint)row[254];                  // ix==256 -> 254; 257.. -> 0
            }
            // ck == 0: ix -8..-1 -> zeros
        }
        *(uint4*)&til[yr * 272 + ck * 8] = u;
    }

    // ---- weights: uniform address -> scalar loads ----
    float w[64];
#pragma unroll
    for (int i = 0; i < 16; i++)
        *(float4*)&w[i * 4] = *(const float4*)&DW[c * 64 + i * 4];

    __syncthreads();

    float inv = gamma[c] * rsqrtf(var[c] + 1e-5f);
    float add = fmaf(-mean[c], inv, beta[c]);

    int xg = tid & 31;       // 32 x-groups * 8 wide = 256
    int yg = tid >> 5;       // 8  y-groups * 4 tall = 32
    int xo = xg * 8;         // output x base (and LDS cc base of reads)
    int yb = yg * 4;         // output y base within tile

    float acc[4][8];
#pragma unroll
    for (int j = 0; j < 4; j++)
#pragma unroll
        for (int p = 0; p < 8; p++) acc[j][p] = 0.f;

#pragma unroll
    for (int r = 0; r < 11; r++) {
        // need cc = xo+5 .. xo+19  (ix = xo+p+kx-3); read cc xo..xo+23 aligned
        const uint4* rp = (const uint4*)&til[(yb + r) * 272 + xo];
        uint4 a0 = rp[0], a1 = rp[1], a2 = rp[2];
        uint u[12] = {a0.x, a0.y, a0.z, a0.w,
                      a1.x, a1.y, a1.z, a1.w,
                      a2.x, a2.y, a2.z, a2.w};
        float vals[16];   // vals[i] = value at cc = xo + 4 + i (uints 2..9)
#pragma unroll
        for (int t = 2; t < 10; t++) {
            vals[2 * (t - 2)]     = __uint_as_float(u[t] << 16);
            vals[2 * (t - 2) + 1] = __uint_as_float(u[t] & 0xffff0000u);
        }
        int jlo = (r - 7 < 0) ? 0 : r - 7;
        int jhi = (r < 3) ? r : 3;
#pragma unroll
        for (int j = jlo; j <= jhi; j++) {
            const float* wr = &w[(r - j) * 8];
#pragma unroll
            for (int kx = 0; kx < 8; kx++) {
                float wt = wr[kx];
#pragma unroll
                for (int p = 0; p < 8; p++)
                    acc[j][p] = fmaf(vals[1 + p + kx], wt, acc[j][p]);
            }
        }
    }

    ushort* Ob = O + ((size_t)(b * 256 + c)) * HWN + (tY + yb) * 256 + xo;
#pragma unroll
    for (int j = 0; j < 4; j++) {
        uint4 st;
        st.x = (uint)f2bf(fmaf(acc[j][0], inv, add))
             | ((uint)f2bf(fmaf(acc[j][1], inv, add)) << 16);
        st.y = (uint)f2bf(fmaf(acc[j][2], inv, add))
             | ((uint)f2bf(fmaf(acc[j][3], inv, add)) << 16);
        st.z = (uint)f2bf(fmaf(acc[j][4], inv, add))
             | ((uint)f2bf(fmaf(acc[j][5], inv, add)) << 16);
        st.w = (uint)f2bf(fmaf(acc[j][6], inv, add))
             | ((uint)f2bf(fmaf(acc[j][7], inv, add)) << 16);
        *(uint4*)&Ob[j * 256] = st;
    }
}

// ---------------------------------------------------------------------------
// Workspace (192 MiB): qp f32 | kp f32 | vp bf16 (aliased by attn out) | dwo.
// biasF (128 KB) lives in the tail of d_out — dead until the final GEMM,
// which overwrites it after win_attn has consumed it.
// ---------------------------------------------------------------------------
extern "C" void kernel_launch(void* const* d_in, const int* in_sizes, int n_in,
                              void* d_out, int out_size, void* d_ws, size_t ws_size,
                              hipStream_t stream)
{
    (void)in_sizes; (void)n_in; (void)ws_size;

    const float* q    = (const float*)d_in[0];
    const float* v    = (const float*)d_in[1];
    const float* Wq   = (const float*)d_in[2];
    const float* Wk   = (const float*)d_in[3];
    const float* Wv   = (const float*)d_in[4];
    const float* bt   = (const float*)d_in[5];
    const float* dw   = (const float*)d_in[6];
    const float* gam  = (const float*)d_in[7];
    const float* bet  = (const float*)d_in[8];
    const float* mean = (const float*)d_in[9];
    const float* var  = (const float*)d_in[10];
    const float* pw   = (const float*)d_in[11];
    const int*   ri   = (const int*)d_in[12];
    float* out = (float*)d_out;

    float*  qp  = (float*)d_ws;
    float*  kp  = qp + (size_t)2 * 64 * HWN;
    ushort* vp  = (ushort*)(kp + (size_t)2 * 64 * HWN);
    ushort* ao  = vp;                          // alias, see win_attn comment
    ushort* dwo = vp + (size_t)2 * 256 * HWN;
    float*  biasF = out + (size_t)out_size - 32768;

    bias_pre<<<128, 256, 0, stream>>>(bt, ri, biasF);
    conv1x1_64<<<512, 256, 0, stream>>>(q, Wq, qp);
    conv1x1_64<<<512, 256, 0, stream>>>(qp, Wk, kp);
    gemm256<float, ushort><<<dim3(512, 2, 2), 256, 0, stream>>>(v, Wv, vp);
    win_attn<<<16384, 64, 0, stream>>>(qp, kp, vp, ao, biasF);
    dwconv_bn<<<dim3(8, 256, 2), 256, 0, stream>>>(ao, dw, gam, bet, mean, var, dwo);
    gemm256<ushort, float><<<dim3(512, 2, 2), 256, 0, stream>>>(dwo, pw, out);
}